// Round 20
// baseline (850.093 us; speedup 1.0000x reference)
//
#include <hip/hip_runtime.h>
#include <math.h>

#define EE 768
#define NS 16
#define RR 48
#define NDEPTH 4
#define NB 2
#define NL 1024
#define NH 3072
#define NV 32000
#define M_ROWS (NB*NL)   // 2048
#define NC 64            // scan chunks
#define CL 16            // chunk length
#define ZPW 896          // z(768) + dt_un(48) + Bu(16) + Cp(16) + pad(48)
#define LOG2E 1.44269504088896f
#define LN2   0.69314718055995f

typedef __attribute__((ext_vector_type(8))) __bf16 bf16x8;
typedef __attribute__((ext_vector_type(4))) __bf16 bf16x4;
typedef __attribute__((ext_vector_type(4))) float f32x4;

__device__ __forceinline__ void gl_lds16(const __bf16* g, __bf16* l){
  __builtin_amdgcn_global_load_lds(
      (const __attribute__((address_space(1))) void*)g,
      (__attribute__((address_space(3))) void*)l, 16, 0, 0);
}

// ---------------- bf16 MFMA GEMM, BK=64, 3-buffer counted-vmcnt pipeline ----------------
enum { BE_STORE=0, BE_BIAS=1, BE_RESID=2, BE_BIAS_RESID=3, BE_BIAS_GELU_B16=4,
       BE_STORE_ZP=5 };

template<int EPI, int BMT, int BNT>
__global__ __launch_bounds__(256) void gemm_bf16(const __bf16* __restrict__ A,
    const __bf16* __restrict__ W, const float* __restrict__ bias,
    void* __restrict__ Cv, float* __restrict__ dtf, float* __restrict__ aux,
    int N, int K, int gx, int gy)
{
  const int nwg = gx*gy;
  const int orig = blockIdx.x;
  const int q = nwg >> 3, r = nwg & 7;
  const int xcd = orig & 7, bse = orig >> 3;
  int wg = (xcd < r ? xcd*(q+1) : r*(q+1) + (xcd-r)*q) + bse;
  const int GN = 16;
  const int per = gy*GN;
  const int g = wg / per;
  const int gstart = g*GN;
  const int gw0 = gx - gstart;
  const int gw = (GN < gw0) ? GN : gw0;
  const int local = wg - g*per;
  const int bx = gstart + local % gw;
  const int by = local / gw;

  constexpr int MFR = BMT/32;
  constexpr int NFR = BNT/32;
  constexpr int LPT = BMT/32 + BNT/32;   // gl_lds instrs per wave per K-tile
  __shared__ __bf16 As[3][BMT][64];
  __shared__ __bf16 Ws[3][BNT][64];
  const int bm = by*BMT, bn = bx*BNT;
  const int tid = threadIdx.x;
  const int w = tid>>6, lane = tid&63;
  const int wr = w>>1, wc = w&1;
  const int fr = lane&15, kg = lane>>4;
  const int sr8 = lane>>3;
  const int sg  = lane&7;
  const int ksrc = ((sg ^ sr8) & 7)*8;

  f32x4 acc[MFR][NFR];
  #pragma unroll
  for (int m=0;m<MFR;m++)
    #pragma unroll
    for (int n=0;n<NFR;n++)
      acc[m][n] = (f32x4){0.f,0.f,0.f,0.f};

  auto stage = [&](int buf, int kt){
    const __bf16* gA = A + (size_t)(bm + w*(BMT/4) + sr8)*K + kt*64 + ksrc;
    #pragma unroll
    for (int c8=0;c8<BMT/32;c8++)
      gl_lds16(gA + (size_t)(c8*8)*K, &As[buf][w*(BMT/4) + c8*8][0]);
    const __bf16* gW = W + (size_t)(bn + w*(BNT/4) + sr8)*K + kt*64 + ksrc;
    #pragma unroll
    for (int c8=0;c8<BNT/32;c8++)
      gl_lds16(gW + (size_t)(c8*8)*K, &Ws[buf][w*(BNT/4) + c8*8][0]);
  };

  const int ntiles = K >> 6;
  stage(0, 0);
  if (ntiles > 1) stage(1, 1);
  for (int t=0; t<ntiles; t++){
    if (t+1 < ntiles){
      if constexpr (LPT==4) asm volatile("s_waitcnt vmcnt(4)\n\ts_barrier" ::: "memory");
      else                  asm volatile("s_waitcnt vmcnt(6)\n\ts_barrier" ::: "memory");
    } else {
      asm volatile("s_waitcnt vmcnt(0)\n\ts_barrier" ::: "memory");
    }
    // issue next-next tile BEFORE compute: buffer (t+2)%3 was last read at
    // compute(t-1); every wave passed that via the barrier above.
    if (t+2 < ntiles) stage((t+2)%3, t+2);
    const int b_ = t % 3;
    #pragma unroll
    for (int kk=0;kk<2;kk++){
      const int sp = (((kg + kk*4) ^ (fr&7)) & 7) * 8;
      bf16x8 af[MFR], bfr[NFR];
      #pragma unroll
      for (int m=0;m<MFR;m++) af[m]  = *(const bf16x8*)&As[b_][wr*(BMT/2) + m*16 + fr][sp];
      #pragma unroll
      for (int n=0;n<NFR;n++) bfr[n] = *(const bf16x8*)&Ws[b_][wc*(BNT/2) + n*16 + fr][sp];
      #pragma unroll
      for (int m=0;m<MFR;m++)
        #pragma unroll
        for (int n=0;n<NFR;n++)
          acc[m][n] = __builtin_amdgcn_mfma_f32_16x16x32_bf16(af[m], bfr[n], acc[m][n], 0,0,0);
    }
  }

  float* Cf = (float*)Cv;
  __bf16* Cb = (__bf16*)Cv;
  #pragma unroll
  for (int m=0;m<MFR;m++){
    int row = bm + wr*(BMT/2) + m*16 + kg*4;
    #pragma unroll
    for (int n=0;n<NFR;n++){
      int col = bn + wc*(BNT/2) + n*16 + fr;
      float bsv = 0.f;
      if (EPI==BE_BIAS || EPI==BE_BIAS_RESID || EPI==BE_BIAS_GELU_B16)
        bsv = bias[col];
      #pragma unroll
      for (int rr2=0;rr2<4;rr2++){
        float v = acc[m][n][rr2];
        size_t idx = (size_t)(row+rr2)*N + col;
        if (EPI==BE_STORE)            Cf[idx] = v;
        else if (EPI==BE_BIAS)        Cf[idx] = v + bsv;
        else if (EPI==BE_RESID)       Cf[idx] += v;
        else if (EPI==BE_BIAS_RESID)  Cf[idx] += v + bsv;
        else if (EPI==BE_BIAS_GELU_B16){
          float xg = v + bsv; Cb[idx] = (__bf16)(0.5f*xg*(1.f+erff(xg*0.70710678118654752f)));
        } else if (EPI==BE_STORE_ZP){
          if (col < 768)                    Cb[(size_t)(row+rr2)*EE + col] = (__bf16)v;
          else if (col < 816)               dtf[(size_t)(row+rr2)*RR + (col-768)] = v;
          else if (col >= 832 && col < 848) aux[(size_t)(row+rr2)*16 + (col-832)] = v;
        }
      }
    }
  }
}

// ---------------- head GEMM: 256x128 tile, 8 waves, 3-buffer counted-vmcnt pipeline ----------------
__global__ __launch_bounds__(512) void gemm_head3p(const __bf16* __restrict__ A,
    const __bf16* __restrict__ W, const float* __restrict__ bias,
    float* __restrict__ C)
{
  const int gx = NV/128, gy = M_ROWS/256;        // 250 x 8 = 2000
  const int nwg = gx*gy;
  const int orig = blockIdx.x;
  const int q = nwg >> 3;
  const int xcd = orig & 7, bse = orig >> 3;
  int wg = xcd*q + bse;
  const int GN = 32;
  const int per = gy*GN;
  const int g = wg / per;
  const int gstart = g*GN;
  const int gw0 = gx - gstart;
  const int gw = (GN < gw0) ? GN : gw0;
  const int local = wg - g*per;
  const int bx = gstart + local % gw;
  const int by = local / gw;

  __shared__ __bf16 Ah[3][256][64];
  __shared__ __bf16 Wh[3][128][64];
  const int bm = by*256, bn = bx*128;
  const int tid = threadIdx.x;
  const int w = tid>>6, lane = tid&63;
  const int wr = w>>1, wc = w&1;
  const int fr = lane&15, kg = lane>>4;
  const int ksrc = (((lane&7) ^ ((lane>>3)&7)) & 7)*8;

  f32x4 acc[4][4];
  #pragma unroll
  for (int m=0;m<4;m++)
    #pragma unroll
    for (int n=0;n<4;n++)
      acc[m][n] = (f32x4){0.f,0.f,0.f,0.f};

  auto stage = [&](int bufp, int kt){
    const __bf16* gA = A + (size_t)(bm + w*8 + (lane>>3))*EE + kt*64 + ksrc;
    #pragma unroll
    for (int j=0;j<4;j++)
      gl_lds16(gA + (size_t)(j*64)*EE, &Ah[bufp][j*64 + w*8][0]);
    const __bf16* gW = W + (size_t)(bn + w*8 + (lane>>3))*EE + kt*64 + ksrc;
    #pragma unroll
    for (int j=0;j<2;j++)
      gl_lds16(gW + (size_t)(j*64)*EE, &Wh[bufp][j*64 + w*8][0]);
  };

  stage(0, 0);
  stage(1, 1);
  #pragma unroll
  for (int t=0;t<12;t++){
    if (t < 11) asm volatile("s_waitcnt vmcnt(6)\n\ts_barrier" ::: "memory");
    else        asm volatile("s_waitcnt vmcnt(0)\n\ts_barrier" ::: "memory");
    if (t+2 < 12) stage((t+2)%3, t+2);   // issue-early: covered by compute below
    const int b_ = t % 3;
    #pragma unroll
    for (int kk=0;kk<2;kk++){
      const int sp = (((kg + kk*4) ^ (fr&7)) & 7) * 8;
      bf16x8 af[4], bfr[4];
      #pragma unroll
      for (int m=0;m<4;m++) af[m]  = *(const bf16x8*)&Ah[b_][wr*64 + m*16 + fr][sp];
      #pragma unroll
      for (int n=0;n<4;n++) bfr[n] = *(const bf16x8*)&Wh[b_][wc*64 + n*16 + fr][sp];
      #pragma unroll
      for (int m=0;m<4;m++)
        #pragma unroll
        for (int n=0;n<4;n++)
          acc[m][n] = __builtin_amdgcn_mfma_f32_16x16x32_bf16(af[m], bfr[n], acc[m][n], 0,0,0);
    }
  }

  #pragma unroll
  for (int m=0;m<4;m++){
    int row = bm + wr*64 + m*16 + kg*4;
    #pragma unroll
    for (int n=0;n<4;n++){
      int col = bn + wc*64 + n*16 + fr;
      float bsv = bias[col];
      #pragma unroll
      for (int rr2=0;rr2<4;rr2++)
        C[(size_t)(row+rr2)*NV + col] = acc[m][n][rr2] + bsv;
    }
  }
}

// ---------------- merged weight conversion ----------------
#define S1E 2752512LL
#define S2E 5111808LL
#define S3E 14548992LL
#define S4E 23986176LL
#define STOT 48562176LL

__global__ void f2b_all(const float* __restrict__ zw, const float* __restrict__ pw,
                        const float* __restrict__ ow, const float* __restrict__ m1,
                        const float* __restrict__ m2, const float* __restrict__ hw,
                        __bf16* __restrict__ o){
  long long idx = ((long long)blockIdx.x*256 + threadIdx.x)*4;
  if (idx >= STOT) return;
  float4 v;
  if (idx < S1E){
    long long layer = idx / (ZPW*EE);
    int rem = (int)(idx - layer*(ZPW*EE));
    int row = rem / EE, col = rem - (rem/EE)*EE;
    if (row < 768)      v = *(const float4*)(zw + ((size_t)layer*EE + row)*EE + col);
    else if (row < 848) v = *(const float4*)(pw + ((size_t)layer*80 + (row-768))*EE + col);
    else                v = make_float4(0.f,0.f,0.f,0.f);
  }
  else if (idx < S2E) v = *(const float4*)(ow + (idx - S1E));
  else if (idx < S3E) v = *(const float4*)(m1 + (idx - S2E));
  else if (idx < S4E) v = *(const float4*)(m2 + (idx - S3E));
  else                v = *(const float4*)(hw + (idx - S4E));
  bf16x4 rb = { (__bf16)v.x, (__bf16)v.y, (__bf16)v.z, (__bf16)v.w };
  *(bf16x4*)(o+idx) = rb;
}

// ---------------- LayerNorm: wave-per-row (4 rows/block), no LDS, no barrier ----------------
__global__ __launch_bounds__(256) void ln_kernel(const float* __restrict__ x,
    const float* __restrict__ gp, const float* __restrict__ bp, __bf16* __restrict__ yb)
{
  int row = blockIdx.x*4 + (threadIdx.x>>6);
  int lane = threadIdx.x & 63;
  const float* xr = x + (size_t)row*EE;
  float4 v0 = *(const float4*)(xr + lane*4);
  float4 v1 = *(const float4*)(xr + 256 + lane*4);
  float4 v2 = *(const float4*)(xr + 512 + lane*4);
  float s = (v0.x+v0.y)+(v0.z+v0.w) + (v1.x+v1.y)+(v1.z+v1.w) + (v2.x+v2.y)+(v2.z+v2.w);
  float q = v0.x*v0.x+v0.y*v0.y+v0.z*v0.z+v0.w*v0.w
          + v1.x*v1.x+v1.y*v1.y+v1.z*v1.z+v1.w*v1.w
          + v2.x*v2.x+v2.y*v2.y+v2.z*v2.z+v2.w*v2.w;
  #pragma unroll
  for (int m=1;m<64;m<<=1){ s += __shfl_xor(s, m, 64); q += __shfl_xor(q, m, 64); }
  float mu  = s*(1.f/768.f);
  float var = q*(1.f/768.f) - mu*mu;
  float inv = 1.0f/sqrtf(var + 1e-5f);
  __bf16* ybr = yb + (size_t)row*EE;
  #pragma unroll
  for (int p=0;p<3;p++){
    const float4 v = (p==0)? v0 : (p==1)? v1 : v2;
    int o = p*256 + lane*4;
    float4 gg = *(const float4*)(gp + o);
    float4 bb = *(const float4*)(bp + o);
    bf16x4 ov = { (__bf16)((v.x-mu)*inv*gg.x + bb.x),
                  (__bf16)((v.y-mu)*inv*gg.y + bb.y),
                  (__bf16)((v.z-mu)*inv*gg.z + bb.z),
                  (__bf16)((v.w-mu)*inv*gg.w + bb.w) };
    *(bf16x4*)(ybr + o) = ov;
  }
}

// ---------------- sinusoidal emb + time MLP ----------------
__global__ void sinemb_kernel(const int* __restrict__ timesteps, float* __restrict__ emb){
  int i = blockIdx.x*256+threadIdx.x;
  if (i >= NB*EE) return;
  int b = i/EE, e = i - b*EE;
  int half = EE/2;
  int j = (e<half)? e : e-half;
  float freq = expf(-logf(10000.f)*(float)j/(float)half);
  float arg = (float)timesteps[b]*freq;
  emb[i] = (e<half)? sinf(arg) : cosf(arg);
}

__global__ void time_mlp1(const float* __restrict__ emb, const float* __restrict__ w1,
                          const float* __restrict__ b1, float* __restrict__ thid){
  int wid = (blockIdx.x*256 + threadIdx.x)>>6;
  int lane = threadIdx.x & 63;
  int b = wid / NH, h = wid - b*NH;
  const float* er = emb + b*EE;
  const float* wr = w1 + (size_t)h*EE;
  float s = 0.f;
  #pragma unroll
  for (int j=0;j<EE/64;j++) s = fmaf(er[j*64+lane], wr[j*64+lane], s);
  #pragma unroll
  for (int m=1;m<64;m<<=1) s += __shfl_xor(s, m, 64);
  if (lane==0){
    s += b1[h];
    thid[wid] = s/(1.f+expf(-s));
  }
}

__global__ void time_mlp2(const float* __restrict__ thid, const float* __restrict__ w2,
                          const float* __restrict__ b2, float* __restrict__ temb){
  int wid = (blockIdx.x*256 + threadIdx.x)>>6;
  int lane = threadIdx.x & 63;
  int b = wid / EE, e = wid - b*EE;
  const float* tr = thid + b*NH;
  const float* wr = w2 + (size_t)e*NH;
  float s = 0.f;
  #pragma unroll
  for (int j=0;j<NH/64;j++) s = fmaf(tr[j*64+lane], wr[j*64+lane], s);
  #pragma unroll
  for (int m=1;m<64;m<<=1) s += __shfl_xor(s, m, 64);
  if (lane==0) temb[wid] = s + b2[e];
}

__global__ void embed_kernel(const int* __restrict__ tokens, const float* __restrict__ tok_emb,
                             const float* __restrict__ temb, float* __restrict__ x){
  int idx = blockIdx.x*256+threadIdx.x;
  int e = idx % EE; int bl = idx / EE; int b = bl / NL;
  int tok = tokens[bl];
  x[idx] = tok_emb[(size_t)tok*EE + e] + temb[b*EE + e];
}

// ---------------- fused scan: coefficients cached in LDS (same-thread scratch) ----------------
__device__ __forceinline__ float dot48(const float* __restrict__ row, const float* wdf){
  float a0=0.f,a1=0.f,a2=0.f,a3=0.f;
  #pragma unroll
  for (int j=0;j<12;j++){
    float4 v = *(const float4*)(row + j*4);
    a0 = fmaf(v.x, wdf[j*4+0], a0);
    a1 = fmaf(v.y, wdf[j*4+1], a1);
    a2 = fmaf(v.z, wdf[j*4+2], a2);
    a3 = fmaf(v.w, wdf[j*4+3], a3);
  }
  return (a0+a1)+(a2+a3);
}
__device__ __forceinline__ float softplus_f(float x){
  return fmaxf(x,0.f) + LN2*log2f(1.f + exp2f(-LOG2E*fabsf(x)));
}
__device__ __forceinline__ float silu_f(float x){
  return x/(1.f + exp2f(-LOG2E*x));
}

// block = (b, 4 e-columns); threads = 4 e x 64 chunks; chain length 1024 = 64*16
__global__ __launch_bounds__(256) void scan_fused(
    const __bf16* __restrict__ xnb, const float* __restrict__ dtun,
    const float* __restrict__ dtw, const float* __restrict__ dtbias,
    const float* __restrict__ cwp, const float* __restrict__ A_log,
    const float* __restrict__ Dp, const float* __restrict__ cpf,
    const __bf16* __restrict__ zgb, __bf16* __restrict__ gb)
{
  __shared__ float Pl[NC][4][NS];
  __shared__ float Sl[NC][4][NS];
  __shared__ float dtc_l[CL][256];
  __shared__ float uc_l[CL+1][256];
  const int tid = threadIdx.x;
  const int e_l = tid & 3, c = tid >> 2;
  const int b  = blockIdx.x / (EE/4);
  const int eg = blockIdx.x % (EE/4);
  const int e  = eg*4 + e_l;

  float wdf[48];
  #pragma unroll
  for (int j=0;j<12;j++){
    float4 v = *(const float4*)(dtw + (size_t)e*RR + j*4);
    wdf[j*4]=v.x; wdf[j*4+1]=v.y; wdf[j*4+2]=v.z; wdf[j*4+3]=v.w;
  }
  float4 cw = *(const float4*)(cwp + e*4);
  float bias = dtbias[e];
  float Dv = Dp[e];
  float Av2[NS], iAv[NS];
  #pragma unroll
  for (int n4=0;n4<4;n4++){
    float4 v = *(const float4*)(A_log + (size_t)e*NS + n4*4);
    float a0=-exp2f(LOG2E*v.x), a1=-exp2f(LOG2E*v.y), a2=-exp2f(LOG2E*v.z), a3=-exp2f(LOG2E*v.w);
    Av2[n4*4+0]=a0*LOG2E; Av2[n4*4+1]=a1*LOG2E; Av2[n4*4+2]=a2*LOG2E; Av2[n4*4+3]=a3*LOG2E;
    iAv[n4*4+0]=1.f/(a0+1e-10f); iAv[n4*4+1]=1.f/(a1+1e-10f);
    iAv[n4*4+2]=1.f/(a2+1e-10f); iAv[n4*4+3]=1.f/(a3+1e-10f);
  }
  const __bf16* xcol = xnb + (size_t)b*NL*EE + e;
  const float* dtrow0 = dtun + (size_t)b*NL*RR;
  const int cs = c*CL;

  // ---- phase 1: per-chunk (sumdt, h) + coefficient capture into LDS ----
  {
    float xw0,xw1,xw2,xw3;
    int prow = (c==0)? 0 : cs-1;
    xw0 = (prow-3>=0)? (float)xcol[(size_t)(prow-3)*EE] : 0.f;
    xw1 = (prow-2>=0)? (float)xcol[(size_t)(prow-2)*EE] : 0.f;
    xw2 = (prow-1>=0)? (float)xcol[(size_t)(prow-1)*EE] : 0.f;
    xw3 = (float)xcol[(size_t)prow*EE];
    float up  = silu_f(cw.x*xw0 + cw.y*xw1 + cw.z*xw2 + cw.w*xw3);
    float dtp_ = softplus_f(dot48(dtrow0 + (size_t)prow*RR, wdf) + bias);
    float h[NS];
    float sumdt = 0.f;
    #pragma unroll
    for (int n=0;n<NS;n++) h[n]=0.f;
    for (int i=0;i<CL;i++){
      int tt = cs+i;
      bool z0 = (tt==0);
      dtc_l[i][tid] = dtp_;
      uc_l[i][tid]  = up;
      sumdt += dtp_;
      #pragma unroll
      for (int n=0;n<NS;n++){
        float at = exp2f(dtp_*Av2[n]);
        float bt = (at-1.f)*iAv[n];
        float s = bt*up;
        h[n] = z0 ? s : fmaf(at, h[n], s);
      }
      if (tt>0){
        xw0=xw1; xw1=xw2; xw2=xw3; xw3 = (float)xcol[(size_t)tt*EE];
        up  = silu_f(cw.x*xw0 + cw.y*xw1 + cw.z*xw2 + cw.w*xw3);
        dtp_ = softplus_f(dot48(dtrow0 + (size_t)tt*RR, wdf) + bias);
      }
    }
    uc_l[CL][tid] = up;
    #pragma unroll
    for (int n4=0;n4<4;n4++){
      float4 pv;
      if (c==0) pv = make_float4(0.f,0.f,0.f,0.f);
      else pv = make_float4(exp2f(Av2[n4*4+0]*sumdt), exp2f(Av2[n4*4+1]*sumdt),
                            exp2f(Av2[n4*4+2]*sumdt), exp2f(Av2[n4*4+3]*sumdt));
      *(float4*)&Pl[c][e_l][n4*4] = pv;
      *(float4*)&Sl[c][e_l][n4*4] = make_float4(h[n4*4],h[n4*4+1],h[n4*4+2],h[n4*4+3]);
    }
  }
  __syncthreads();
  // ---- phase 2: in-LDS combine across chunks ----
  if (tid < 64){
    int el2 = tid & 3, n = tid >> 2;
    float hh = 0.f;
    for (int cc=0; cc<NC; cc++){
      float pp = Pl[cc][el2][n], ss = Sl[cc][el2][n];
      Pl[cc][el2][n] = hh;
      hh = fmaf(pp, hh, ss);
    }
  }
  __syncthreads();
  // ---- phase 3: re-walk chunk from LDS-cached coefficients, emit g ----
  {
    float h[NS];
    #pragma unroll
    for (int n4=0;n4<4;n4++){
      float4 v = *(const float4*)&Pl[c][e_l][n4*4];
      h[n4*4]=v.x; h[n4*4+1]=v.y; h[n4*4+2]=v.z; h[n4*4+3]=v.w;
    }
    #pragma unroll
    for (int i=0;i<CL;i++){
      int tt = cs+i;
      bool z0 = (tt==0);
      float dtp_ = dtc_l[i][tid];
      float up   = uc_l[i][tid];
      float ucur = uc_l[i+1][tid];
      #pragma unroll
      for (int n=0;n<NS;n++){
        float at = exp2f(dtp_*Av2[n]);
        float bt = (at-1.f)*iAv[n];
        float s = bt*up;
        h[n] = z0 ? s : fmaf(at, h[n], s);
      }
      const float* cpr = cpf + (size_t)(b*NL+tt)*16;
      float y = 0.f;
      #pragma unroll
      for (int n4=0;n4<4;n4++){
        float4 cv = *(const float4*)(cpr + n4*4);
        y = fmaf(cv.x, h[n4*4], y);   y = fmaf(cv.y, h[n4*4+1], y);
        y = fmaf(cv.z, h[n4*4+2], y); y = fmaf(cv.w, h[n4*4+3], y);
      }
      float zv = (float)zgb[(size_t)(b*NL+tt)*EE + e];
      gb[(size_t)(b*NL+tt)*EE + e] = (__bf16)((y + ucur*Dv)*silu_f(zv));
    }
  }
}

extern "C" void kernel_launch(void* const* d_in, const int* in_sizes, int n_in,
                              void* d_out, int out_size, void* d_ws, size_t ws_size,
                              hipStream_t stream) {
  const int*   tokens    = (const int*)d_in[0];
  const int*   timesteps = (const int*)d_in[1];
  const float* tok_emb   = (const float*)d_in[2];
  const float* time_w1   = (const float*)d_in[3];
  const float* time_b1   = (const float*)d_in[4];
  const float* time_w2   = (const float*)d_in[5];
  const float* time_b2   = (const float*)d_in[6];
  const float* ln1_g     = (const float*)d_in[7];
  const float* ln1_b     = (const float*)d_in[8];
  const float* z_w       = (const float*)d_in[9];
  const float* p_w       = (const float*)d_in[10];
  const float* conv_w    = (const float*)d_in[11];
  const float* dtp_w     = (const float*)d_in[12];
  const float* dtp_b     = (const float*)d_in[13];
  const float* A_log     = (const float*)d_in[14];
  const float* D_param   = (const float*)d_in[15];
  const float* out_w     = (const float*)d_in[16];
  const float* ln2_g     = (const float*)d_in[17];
  const float* ln2_b     = (const float*)d_in[18];
  const float* mlp_w1    = (const float*)d_in[19];
  const float* mlp_b1    = (const float*)d_in[20];
  const float* mlp_w2    = (const float*)d_in[21];
  const float* mlp_b2    = (const float*)d_in[22];
  const float* lnout_g   = (const float*)d_in[23];
  const float* lnout_b   = (const float*)d_in[24];
  const float* head_w    = (const float*)d_in[25];
  const float* head_b    = (const float*)d_in[26];
  float* out = (float*)d_out;

  float* ws = (float*)d_ws;
  float* x      = ws;
  float* cpf    = x    + (size_t)M_ROWS*EE;
  float* dtun   = cpf  + (size_t)M_ROWS*16;
  float* emb    = dtun + (size_t)M_ROWS*RR;
  float* thid   = emb + NB*EE;
  __bf16* xnb   = (__bf16*)(thid + NB*NH);
  __bf16* zgb   = xnb + (size_t)M_ROWS*EE;
  __bf16* gb    = zgb + (size_t)M_ROWS*EE;
  __bf16* hidb  = gb  + (size_t)M_ROWS*EE;
  __bf16* wzp   = hidb + (size_t)M_ROWS*NH;
  __bf16* wout  = wzp  + (size_t)NDEPTH*ZPW*EE;
  __bf16* wm1   = wout + (size_t)NDEPTH*EE*EE;
  __bf16* wm2   = wm1  + (size_t)NDEPTH*NH*EE;
  __bf16* whead = wm2  + (size_t)NDEPTH*EE*NH;

  f2b_all<<<(int)(STOT/4/256), 256, 0, stream>>>(z_w, p_w, out_w, mlp_w1, mlp_w2, head_w, wzp);

  sinemb_kernel<<<(NB*EE+255)/256, 256, 0, stream>>>(timesteps, emb);
  time_mlp1<<<NB*NH/4, 256, 0, stream>>>(emb, time_w1, time_b1, thid);
  time_mlp2<<<NB*EE/4, 256, 0, stream>>>(thid, time_w2, time_b2, emb);
  embed_kernel<<<M_ROWS*EE/256, 256, 0, stream>>>(tokens, tok_emb, emb, x);

  const int scan_grid = NB*EE/4;

  for (int i=0;i<NDEPTH;i++){
    const float* dtw = dtp_w + (size_t)i*EE*RR;
    const float* dtb = dtp_b + i*EE;
    const float* cwp = conv_w + (size_t)i*EE*4;
    const float* al  = A_log + (size_t)i*EE*NS;
    ln_kernel<<<M_ROWS/4, 256, 0, stream>>>(x, ln1_g + i*EE, ln1_b + i*EE, xnb);
    gemm_bf16<BE_STORE_ZP,64,64><<<14*32, 256, 0, stream>>>(
        xnb, wzp + (size_t)i*ZPW*EE, nullptr, zgb, dtun, cpf, ZPW, EE, 14, 32);
    scan_fused<<<scan_grid, 256, 0, stream>>>(xnb, dtun, dtw, dtb, cwp, al,
        D_param + i*EE, cpf, zgb, gb);
    gemm_bf16<BE_RESID,64,64><<<12*32, 256, 0, stream>>>(
        gb, wout + (size_t)i*EE*EE, nullptr, x, nullptr, nullptr, EE, EE, 12, 32);
    ln_kernel<<<M_ROWS/4, 256, 0, stream>>>(x, ln2_g + i*EE, ln2_b + i*EE, xnb);
    gemm_bf16<BE_BIAS_GELU_B16,64,128><<<24*32, 256, 0, stream>>>(
        xnb, wm1 + (size_t)i*NH*EE, mlp_b1 + i*NH, hidb, nullptr, nullptr, NH, EE, 24, 32);
    gemm_bf16<BE_BIAS_RESID,64,64><<<12*32, 256, 0, stream>>>(
        hidb, wm2 + (size_t)i*EE*NH, mlp_b2 + i*EE, x, nullptr, nullptr, EE, NH, 12, 32);
  }
  ln_kernel<<<M_ROWS/4, 256, 0, stream>>>(x, lnout_g, lnout_b, xnb);
  gemm_head3p<<<(NV/128)*(M_ROWS/256), 512, 0, stream>>>(xnb, whead, head_b, out);
}

// Round 21
// 773.233 us; speedup vs baseline: 1.0994x; 1.0994x over previous
//
#include <hip/hip_runtime.h>
#include <math.h>

#define EE 768
#define NS 16
#define RR 48
#define NDEPTH 4
#define NB 2
#define NL 1024
#define NH 3072
#define NV 32000
#define M_ROWS (NB*NL)   // 2048
#define NC 64            // scan chunks
#define CL 16            // chunk length
#define ZPW 896          // z(768) + dt_un(48) + Bu(16) + Cp(16) + pad(48)
#define LOG2E 1.44269504088896f
#define LN2   0.69314718055995f

typedef __attribute__((ext_vector_type(8))) __bf16 bf16x8;
typedef __attribute__((ext_vector_type(4))) __bf16 bf16x4;
typedef __attribute__((ext_vector_type(4))) float f32x4;

__device__ __forceinline__ void gl_lds16(const __bf16* g, __bf16* l){
  __builtin_amdgcn_global_load_lds(
      (const __attribute__((address_space(1))) void*)g,
      (__attribute__((address_space(3))) void*)l, 16, 0, 0);
}

// ---------------- bf16 MFMA GEMM, BK=64, 3-buffer counted-vmcnt pipeline ----------------
enum { BE_STORE=0, BE_BIAS=1, BE_RESID=2, BE_BIAS_RESID=3, BE_BIAS_GELU_B16=4,
       BE_STORE_ZP=5 };

template<int EPI, int BMT, int BNT>
__global__ __launch_bounds__(256) void gemm_bf16(const __bf16* __restrict__ A,
    const __bf16* __restrict__ W, const float* __restrict__ bias,
    void* __restrict__ Cv, float* __restrict__ dtf, float* __restrict__ aux,
    int N, int K, int gx, int gy)
{
  const int nwg = gx*gy;
  const int orig = blockIdx.x;
  const int q = nwg >> 3, r = nwg & 7;
  const int xcd = orig & 7, bse = orig >> 3;
  int wg = (xcd < r ? xcd*(q+1) : r*(q+1) + (xcd-r)*q) + bse;
  const int GN = 16;
  const int per = gy*GN;
  const int g = wg / per;
  const int gstart = g*GN;
  const int gw0 = gx - gstart;
  const int gw = (GN < gw0) ? GN : gw0;
  const int local = wg - g*per;
  const int bx = gstart + local % gw;
  const int by = local / gw;

  constexpr int MFR = BMT/32;
  constexpr int NFR = BNT/32;
  constexpr int LPT = BMT/32 + BNT/32;   // gl_lds instrs per wave per K-tile
  __shared__ __bf16 As[3][BMT][64];
  __shared__ __bf16 Ws[3][BNT][64];
  const int bm = by*BMT, bn = bx*BNT;
  const int tid = threadIdx.x;
  const int w = tid>>6, lane = tid&63;
  const int wr = w>>1, wc = w&1;
  const int fr = lane&15, kg = lane>>4;
  const int sr8 = lane>>3;
  const int sg  = lane&7;
  const int ksrc = ((sg ^ sr8) & 7)*8;

  f32x4 acc[MFR][NFR];
  #pragma unroll
  for (int m=0;m<MFR;m++)
    #pragma unroll
    for (int n=0;n<NFR;n++)
      acc[m][n] = (f32x4){0.f,0.f,0.f,0.f};

  auto stage = [&](int buf, int kt){
    const __bf16* gA = A + (size_t)(bm + w*(BMT/4) + sr8)*K + kt*64 + ksrc;
    #pragma unroll
    for (int c8=0;c8<BMT/32;c8++)
      gl_lds16(gA + (size_t)(c8*8)*K, &As[buf][w*(BMT/4) + c8*8][0]);
    const __bf16* gW = W + (size_t)(bn + w*(BNT/4) + sr8)*K + kt*64 + ksrc;
    #pragma unroll
    for (int c8=0;c8<BNT/32;c8++)
      gl_lds16(gW + (size_t)(c8*8)*K, &Ws[buf][w*(BNT/4) + c8*8][0]);
  };

  const int ntiles = K >> 6;
  stage(0, 0);
  if (ntiles > 1) stage(1, 1);
  for (int t=0; t<ntiles; t++){
    if (t+1 < ntiles){
      if constexpr (LPT==4) asm volatile("s_waitcnt vmcnt(4)\n\ts_barrier" ::: "memory");
      else                  asm volatile("s_waitcnt vmcnt(6)\n\ts_barrier" ::: "memory");
    } else {
      asm volatile("s_waitcnt vmcnt(0)\n\ts_barrier" ::: "memory");
    }
    const int b_ = t % 3;
    #pragma unroll
    for (int kk=0;kk<2;kk++){
      const int sp = (((kg + kk*4) ^ (fr&7)) & 7) * 8;
      bf16x8 af[MFR], bfr[NFR];
      #pragma unroll
      for (int m=0;m<MFR;m++) af[m]  = *(const bf16x8*)&As[b_][wr*(BMT/2) + m*16 + fr][sp];
      #pragma unroll
      for (int n=0;n<NFR;n++) bfr[n] = *(const bf16x8*)&Ws[b_][wc*(BNT/2) + n*16 + fr][sp];
      #pragma unroll
      for (int m=0;m<MFR;m++)
        #pragma unroll
        for (int n=0;n<NFR;n++)
          acc[m][n] = __builtin_amdgcn_mfma_f32_16x16x32_bf16(af[m], bfr[n], acc[m][n], 0,0,0);
    }
    if (t+2 < ntiles) stage((t+2)%3, t+2);   // buf (t+2)%3 last read at t-1; barrier above separates
  }

  float* Cf = (float*)Cv;
  __bf16* Cb = (__bf16*)Cv;
  #pragma unroll
  for (int m=0;m<MFR;m++){
    int row = bm + wr*(BMT/2) + m*16 + kg*4;
    #pragma unroll
    for (int n=0;n<NFR;n++){
      int col = bn + wc*(BNT/2) + n*16 + fr;
      float bsv = 0.f;
      if (EPI==BE_BIAS || EPI==BE_BIAS_RESID || EPI==BE_BIAS_GELU_B16)
        bsv = bias[col];
      #pragma unroll
      for (int rr2=0;rr2<4;rr2++){
        float v = acc[m][n][rr2];
        size_t idx = (size_t)(row+rr2)*N + col;
        if (EPI==BE_STORE)            Cf[idx] = v;
        else if (EPI==BE_BIAS)        Cf[idx] = v + bsv;
        else if (EPI==BE_RESID)       Cf[idx] += v;
        else if (EPI==BE_BIAS_RESID)  Cf[idx] += v + bsv;
        else if (EPI==BE_BIAS_GELU_B16){
          float xg = v + bsv; Cb[idx] = (__bf16)(0.5f*xg*(1.f+erff(xg*0.70710678118654752f)));
        } else if (EPI==BE_STORE_ZP){
          if (col < 768)                    Cb[(size_t)(row+rr2)*EE + col] = (__bf16)v;
          else if (col < 816)               dtf[(size_t)(row+rr2)*RR + (col-768)] = v;
          else if (col >= 832 && col < 848) aux[(size_t)(row+rr2)*16 + (col-832)] = v;
        }
      }
    }
  }
}

// ---------------- head GEMM: 256x128 tile, 8 waves, 3-buffer counted-vmcnt pipeline ----------------
__global__ __launch_bounds__(512) void gemm_head3p(const __bf16* __restrict__ A,
    const __bf16* __restrict__ W, const float* __restrict__ bias,
    float* __restrict__ C)
{
  const int gx = NV/128, gy = M_ROWS/256;        // 250 x 8 = 2000
  const int nwg = gx*gy;
  const int orig = blockIdx.x;
  const int q = nwg >> 3;
  const int xcd = orig & 7, bse = orig >> 3;
  int wg = xcd*q + bse;
  const int GN = 32;
  const int per = gy*GN;
  const int g = wg / per;
  const int gstart = g*GN;
  const int gw0 = gx - gstart;
  const int gw = (GN < gw0) ? GN : gw0;
  const int local = wg - g*per;
  const int bx = gstart + local % gw;
  const int by = local / gw;

  __shared__ __bf16 Ah[3][256][64];
  __shared__ __bf16 Wh[3][128][64];
  const int bm = by*256, bn = bx*128;
  const int tid = threadIdx.x;
  const int w = tid>>6, lane = tid&63;
  const int wr = w>>1, wc = w&1;
  const int fr = lane&15, kg = lane>>4;
  const int ksrc = (((lane&7) ^ ((lane>>3)&7)) & 7)*8;

  f32x4 acc[4][4];
  #pragma unroll
  for (int m=0;m<4;m++)
    #pragma unroll
    for (int n=0;n<4;n++)
      acc[m][n] = (f32x4){0.f,0.f,0.f,0.f};

  auto stage = [&](int bufp, int kt){
    const __bf16* gA = A + (size_t)(bm + w*8 + (lane>>3))*EE + kt*64 + ksrc;
    #pragma unroll
    for (int j=0;j<4;j++)
      gl_lds16(gA + (size_t)(j*64)*EE, &Ah[bufp][j*64 + w*8][0]);
    const __bf16* gW = W + (size_t)(bn + w*8 + (lane>>3))*EE + kt*64 + ksrc;
    #pragma unroll
    for (int j=0;j<2;j++)
      gl_lds16(gW + (size_t)(j*64)*EE, &Wh[bufp][j*64 + w*8][0]);
  };

  stage(0, 0);
  stage(1, 1);
  #pragma unroll
  for (int t=0;t<12;t++){
    if (t < 11) asm volatile("s_waitcnt vmcnt(6)\n\ts_barrier" ::: "memory");
    else        asm volatile("s_waitcnt vmcnt(0)\n\ts_barrier" ::: "memory");
    const int b_ = t % 3;
    #pragma unroll
    for (int kk=0;kk<2;kk++){
      const int sp = (((kg + kk*4) ^ (fr&7)) & 7) * 8;
      bf16x8 af[4], bfr[4];
      #pragma unroll
      for (int m=0;m<4;m++) af[m]  = *(const bf16x8*)&Ah[b_][wr*64 + m*16 + fr][sp];
      #pragma unroll
      for (int n=0;n<4;n++) bfr[n] = *(const bf16x8*)&Wh[b_][wc*64 + n*16 + fr][sp];
      #pragma unroll
      for (int m=0;m<4;m++)
        #pragma unroll
        for (int n=0;n<4;n++)
          acc[m][n] = __builtin_amdgcn_mfma_f32_16x16x32_bf16(af[m], bfr[n], acc[m][n], 0,0,0);
    }
    if (t+2 < 12) stage((t+2)%3, t+2);
  }

  #pragma unroll
  for (int m=0;m<4;m++){
    int row = bm + wr*64 + m*16 + kg*4;
    #pragma unroll
    for (int n=0;n<4;n++){
      int col = bn + wc*64 + n*16 + fr;
      float bsv = bias[col];
      #pragma unroll
      for (int rr2=0;rr2<4;rr2++)
        C[(size_t)(row+rr2)*NV + col] = acc[m][n][rr2] + bsv;
    }
  }
}

// ---------------- merged weight conversion ----------------
#define S1E 2752512LL
#define S2E 5111808LL
#define S3E 14548992LL
#define S4E 23986176LL
#define STOT 48562176LL

__global__ void f2b_all(const float* __restrict__ zw, const float* __restrict__ pw,
                        const float* __restrict__ ow, const float* __restrict__ m1,
                        const float* __restrict__ m2, const float* __restrict__ hw,
                        __bf16* __restrict__ o){
  long long idx = ((long long)blockIdx.x*256 + threadIdx.x)*4;
  if (idx >= STOT) return;
  float4 v;
  if (idx < S1E){
    long long layer = idx / (ZPW*EE);
    int rem = (int)(idx - layer*(ZPW*EE));
    int row = rem / EE, col = rem - (rem/EE)*EE;
    if (row < 768)      v = *(const float4*)(zw + ((size_t)layer*EE + row)*EE + col);
    else if (row < 848) v = *(const float4*)(pw + ((size_t)layer*80 + (row-768))*EE + col);
    else                v = make_float4(0.f,0.f,0.f,0.f);
  }
  else if (idx < S2E) v = *(const float4*)(ow + (idx - S1E));
  else if (idx < S3E) v = *(const float4*)(m1 + (idx - S2E));
  else if (idx < S4E) v = *(const float4*)(m2 + (idx - S3E));
  else                v = *(const float4*)(hw + (idx - S4E));
  bf16x4 rb = { (__bf16)v.x, (__bf16)v.y, (__bf16)v.z, (__bf16)v.w };
  *(bf16x4*)(o+idx) = rb;
}

// ---------------- LayerNorm: wave-per-row (4 rows/block), no LDS, no barrier ----------------
__global__ __launch_bounds__(256) void ln_kernel(const float* __restrict__ x,
    const float* __restrict__ gp, const float* __restrict__ bp, __bf16* __restrict__ yb)
{
  int row = blockIdx.x*4 + (threadIdx.x>>6);
  int lane = threadIdx.x & 63;
  const float* xr = x + (size_t)row*EE;
  float4 v0 = *(const float4*)(xr + lane*4);
  float4 v1 = *(const float4*)(xr + 256 + lane*4);
  float4 v2 = *(const float4*)(xr + 512 + lane*4);
  float s = (v0.x+v0.y)+(v0.z+v0.w) + (v1.x+v1.y)+(v1.z+v1.w) + (v2.x+v2.y)+(v2.z+v2.w);
  float q = v0.x*v0.x+v0.y*v0.y+v0.z*v0.z+v0.w*v0.w
          + v1.x*v1.x+v1.y*v1.y+v1.z*v1.z+v1.w*v1.w
          + v2.x*v2.x+v2.y*v2.y+v2.z*v2.z+v2.w*v2.w;
  #pragma unroll
  for (int m=1;m<64;m<<=1){ s += __shfl_xor(s, m, 64); q += __shfl_xor(q, m, 64); }
  float mu  = s*(1.f/768.f);
  float var = q*(1.f/768.f) - mu*mu;
  float inv = 1.0f/sqrtf(var + 1e-5f);
  __bf16* ybr = yb + (size_t)row*EE;
  #pragma unroll
  for (int p=0;p<3;p++){
    const float4 v = (p==0)? v0 : (p==1)? v1 : v2;
    int o = p*256 + lane*4;
    float4 gg = *(const float4*)(gp + o);
    float4 bb = *(const float4*)(bp + o);
    bf16x4 ov = { (__bf16)((v.x-mu)*inv*gg.x + bb.x),
                  (__bf16)((v.y-mu)*inv*gg.y + bb.y),
                  (__bf16)((v.z-mu)*inv*gg.z + bb.z),
                  (__bf16)((v.w-mu)*inv*gg.w + bb.w) };
    *(bf16x4*)(ybr + o) = ov;
  }
}

// ---------------- sinusoidal emb + time MLP ----------------
__global__ void sinemb_kernel(const int* __restrict__ timesteps, float* __restrict__ emb){
  int i = blockIdx.x*256+threadIdx.x;
  if (i >= NB*EE) return;
  int b = i/EE, e = i - b*EE;
  int half = EE/2;
  int j = (e<half)? e : e-half;
  float freq = expf(-logf(10000.f)*(float)j/(float)half);
  float arg = (float)timesteps[b]*freq;
  emb[i] = (e<half)? sinf(arg) : cosf(arg);
}

__global__ void time_mlp1(const float* __restrict__ emb, const float* __restrict__ w1,
                          const float* __restrict__ b1, float* __restrict__ thid){
  int wid = (blockIdx.x*256 + threadIdx.x)>>6;
  int lane = threadIdx.x & 63;
  int b = wid / NH, h = wid - b*NH;
  const float* er = emb + b*EE;
  const float* wr = w1 + (size_t)h*EE;
  float s = 0.f;
  #pragma unroll
  for (int j=0;j<EE/64;j++) s = fmaf(er[j*64+lane], wr[j*64+lane], s);
  #pragma unroll
  for (int m=1;m<64;m<<=1) s += __shfl_xor(s, m, 64);
  if (lane==0){
    s += b1[h];
    thid[wid] = s/(1.f+expf(-s));
  }
}

__global__ void time_mlp2(const float* __restrict__ thid, const float* __restrict__ w2,
                          const float* __restrict__ b2, float* __restrict__ temb){
  int wid = (blockIdx.x*256 + threadIdx.x)>>6;
  int lane = threadIdx.x & 63;
  int b = wid / EE, e = wid - b*EE;
  const float* tr = thid + b*NH;
  const float* wr = w2 + (size_t)e*NH;
  float s = 0.f;
  #pragma unroll
  for (int j=0;j<NH/64;j++) s = fmaf(tr[j*64+lane], wr[j*64+lane], s);
  #pragma unroll
  for (int m=1;m<64;m<<=1) s += __shfl_xor(s, m, 64);
  if (lane==0) temb[wid] = s + b2[e];
}

__global__ void embed_kernel(const int* __restrict__ tokens, const float* __restrict__ tok_emb,
                             const float* __restrict__ temb, float* __restrict__ x){
  int idx = blockIdx.x*256+threadIdx.x;
  int e = idx % EE; int bl = idx / EE; int b = bl / NL;
  int tok = tokens[bl];
  x[idx] = tok_emb[(size_t)tok*EE + e] + temb[b*EE + e];
}

// ---------------- fused scan: coefficients cached in LDS (same-thread scratch) ----------------
__device__ __forceinline__ float dot48(const float* __restrict__ row, const float* wdf){
  float a0=0.f,a1=0.f,a2=0.f,a3=0.f;
  #pragma unroll
  for (int j=0;j<12;j++){
    float4 v = *(const float4*)(row + j*4);
    a0 = fmaf(v.x, wdf[j*4+0], a0);
    a1 = fmaf(v.y, wdf[j*4+1], a1);
    a2 = fmaf(v.z, wdf[j*4+2], a2);
    a3 = fmaf(v.w, wdf[j*4+3], a3);
  }
  return (a0+a1)+(a2+a3);
}
__device__ __forceinline__ float softplus_f(float x){
  return fmaxf(x,0.f) + LN2*log2f(1.f + exp2f(-LOG2E*fabsf(x)));
}
__device__ __forceinline__ float silu_f(float x){
  return x/(1.f + exp2f(-LOG2E*x));
}

// block = (b, 4 e-columns); threads = 4 e x 64 chunks; chain length 1024 = 64*16
__global__ __launch_bounds__(256) void scan_fused(
    const __bf16* __restrict__ xnb, const float* __restrict__ dtun,
    const float* __restrict__ dtw, const float* __restrict__ dtbias,
    const float* __restrict__ cwp, const float* __restrict__ A_log,
    const float* __restrict__ Dp, const float* __restrict__ cpf,
    const __bf16* __restrict__ zgb, __bf16* __restrict__ gb)
{
  __shared__ float Pl[NC][4][NS];
  __shared__ float Sl[NC][4][NS];
  __shared__ float dtc_l[CL][256];
  __shared__ float uc_l[CL+1][256];
  const int tid = threadIdx.x;
  const int e_l = tid & 3, c = tid >> 2;
  const int b  = blockIdx.x / (EE/4);
  const int eg = blockIdx.x % (EE/4);
  const int e  = eg*4 + e_l;

  float wdf[48];
  #pragma unroll
  for (int j=0;j<12;j++){
    float4 v = *(const float4*)(dtw + (size_t)e*RR + j*4);
    wdf[j*4]=v.x; wdf[j*4+1]=v.y; wdf[j*4+2]=v.z; wdf[j*4+3]=v.w;
  }
  float4 cw = *(const float4*)(cwp + e*4);
  float bias = dtbias[e];
  float Dv = Dp[e];
  float Av2[NS], iAv[NS];
  #pragma unroll
  for (int n4=0;n4<4;n4++){
    float4 v = *(const float4*)(A_log + (size_t)e*NS + n4*4);
    float a0=-exp2f(LOG2E*v.x), a1=-exp2f(LOG2E*v.y), a2=-exp2f(LOG2E*v.z), a3=-exp2f(LOG2E*v.w);
    Av2[n4*4+0]=a0*LOG2E; Av2[n4*4+1]=a1*LOG2E; Av2[n4*4+2]=a2*LOG2E; Av2[n4*4+3]=a3*LOG2E;
    iAv[n4*4+0]=1.f/(a0+1e-10f); iAv[n4*4+1]=1.f/(a1+1e-10f);
    iAv[n4*4+2]=1.f/(a2+1e-10f); iAv[n4*4+3]=1.f/(a3+1e-10f);
  }
  const __bf16* xcol = xnb + (size_t)b*NL*EE + e;
  const float* dtrow0 = dtun + (size_t)b*NL*RR;
  const int cs = c*CL;

  // ---- phase 1: per-chunk (sumdt, h) + coefficient capture into LDS ----
  {
    float xw0,xw1,xw2,xw3;
    int prow = (c==0)? 0 : cs-1;
    xw0 = (prow-3>=0)? (float)xcol[(size_t)(prow-3)*EE] : 0.f;
    xw1 = (prow-2>=0)? (float)xcol[(size_t)(prow-2)*EE] : 0.f;
    xw2 = (prow-1>=0)? (float)xcol[(size_t)(prow-1)*EE] : 0.f;
    xw3 = (float)xcol[(size_t)prow*EE];
    float up  = silu_f(cw.x*xw0 + cw.y*xw1 + cw.z*xw2 + cw.w*xw3);
    float dtp_ = softplus_f(dot48(dtrow0 + (size_t)prow*RR, wdf) + bias);
    float h[NS];
    float sumdt = 0.f;
    #pragma unroll
    for (int n=0;n<NS;n++) h[n]=0.f;
    for (int i=0;i<CL;i++){
      int tt = cs+i;
      bool z0 = (tt==0);
      dtc_l[i][tid] = dtp_;
      uc_l[i][tid]  = up;
      sumdt += dtp_;
      #pragma unroll
      for (int n=0;n<NS;n++){
        float at = exp2f(dtp_*Av2[n]);
        float bt = (at-1.f)*iAv[n];
        float s = bt*up;
        h[n] = z0 ? s : fmaf(at, h[n], s);
      }
      if (tt>0){
        xw0=xw1; xw1=xw2; xw2=xw3; xw3 = (float)xcol[(size_t)tt*EE];
        up  = silu_f(cw.x*xw0 + cw.y*xw1 + cw.z*xw2 + cw.w*xw3);
        dtp_ = softplus_f(dot48(dtrow0 + (size_t)tt*RR, wdf) + bias);
      }
    }
    uc_l[CL][tid] = up;
    #pragma unroll
    for (int n4=0;n4<4;n4++){
      float4 pv;
      if (c==0) pv = make_float4(0.f,0.f,0.f,0.f);
      else pv = make_float4(exp2f(Av2[n4*4+0]*sumdt), exp2f(Av2[n4*4+1]*sumdt),
                            exp2f(Av2[n4*4+2]*sumdt), exp2f(Av2[n4*4+3]*sumdt));
      *(float4*)&Pl[c][e_l][n4*4] = pv;
      *(float4*)&Sl[c][e_l][n4*4] = make_float4(h[n4*4],h[n4*4+1],h[n4*4+2],h[n4*4+3]);
    }
  }
  __syncthreads();
  // ---- phase 2: in-LDS combine across chunks ----
  if (tid < 64){
    int el2 = tid & 3, n = tid >> 2;
    float hh = 0.f;
    for (int cc=0; cc<NC; cc++){
      float pp = Pl[cc][el2][n], ss = Sl[cc][el2][n];
      Pl[cc][el2][n] = hh;
      hh = fmaf(pp, hh, ss);
    }
  }
  __syncthreads();
  // ---- phase 3: re-walk chunk from LDS-cached coefficients, emit g ----
  {
    float h[NS];
    #pragma unroll
    for (int n4=0;n4<4;n4++){
      float4 v = *(const float4*)&Pl[c][e_l][n4*4];
      h[n4*4]=v.x; h[n4*4+1]=v.y; h[n4*4+2]=v.z; h[n4*4+3]=v.w;
    }
    #pragma unroll
    for (int i=0;i<CL;i++){
      int tt = cs+i;
      bool z0 = (tt==0);
      float dtp_ = dtc_l[i][tid];
      float up   = uc_l[i][tid];
      float ucur = uc_l[i+1][tid];
      #pragma unroll
      for (int n=0;n<NS;n++){
        float at = exp2f(dtp_*Av2[n]);
        float bt = (at-1.f)*iAv[n];
        float s = bt*up;
        h[n] = z0 ? s : fmaf(at, h[n], s);
      }
      const float* cpr = cpf + (size_t)(b*NL+tt)*16;
      float y = 0.f;
      #pragma unroll
      for (int n4=0;n4<4;n4++){
        float4 cv = *(const float4*)(cpr + n4*4);
        y = fmaf(cv.x, h[n4*4], y);   y = fmaf(cv.y, h[n4*4+1], y);
        y = fmaf(cv.z, h[n4*4+2], y); y = fmaf(cv.w, h[n4*4+3], y);
      }
      float zv = (float)zgb[(size_t)(b*NL+tt)*EE + e];
      gb[(size_t)(b*NL+tt)*EE + e] = (__bf16)((y + ucur*Dv)*silu_f(zv));
    }
  }
}

extern "C" void kernel_launch(void* const* d_in, const int* in_sizes, int n_in,
                              void* d_out, int out_size, void* d_ws, size_t ws_size,
                              hipStream_t stream) {
  const int*   tokens    = (const int*)d_in[0];
  const int*   timesteps = (const int*)d_in[1];
  const float* tok_emb   = (const float*)d_in[2];
  const float* time_w1   = (const float*)d_in[3];
  const float* time_b1   = (const float*)d_in[4];
  const float* time_w2   = (const float*)d_in[5];
  const float* time_b2   = (const float*)d_in[6];
  const float* ln1_g     = (const float*)d_in[7];
  const float* ln1_b     = (const float*)d_in[8];
  const float* z_w       = (const float*)d_in[9];
  const float* p_w       = (const float*)d_in[10];
  const float* conv_w    = (const float*)d_in[11];
  const float* dtp_w     = (const float*)d_in[12];
  const float* dtp_b     = (const float*)d_in[13];
  const float* A_log     = (const float*)d_in[14];
  const float* D_param   = (const float*)d_in[15];
  const float* out_w     = (const float*)d_in[16];
  const float* ln2_g     = (const float*)d_in[17];
  const float* ln2_b     = (const float*)d_in[18];
  const float* mlp_w1    = (const float*)d_in[19];
  const float* mlp_b1    = (const float*)d_in[20];
  const float* mlp_w2    = (const float*)d_in[21];
  const float* mlp_b2    = (const float*)d_in[22];
  const float* lnout_g   = (const float*)d_in[23];
  const float* lnout_b   = (const float*)d_in[24];
  const float* head_w    = (const float*)d_in[25];
  const float* head_b    = (const float*)d_in[26];
  float* out = (float*)d_out;

  float* ws = (float*)d_ws;
  float* x      = ws;
  float* cpf    = x    + (size_t)M_ROWS*EE;
  float* dtun   = cpf  + (size_t)M_ROWS*16;
  float* emb    = dtun + (size_t)M_ROWS*RR;
  float* thid   = emb + NB*EE;
  __bf16* xnb   = (__bf16*)(thid + NB*NH);
  __bf16* zgb   = xnb + (size_t)M_ROWS*EE;
  __bf16* gb    = zgb + (size_t)M_ROWS*EE;
  __bf16* hidb  = gb  + (size_t)M_ROWS*EE;
  __bf16* wzp   = hidb + (size_t)M_ROWS*NH;
  __bf16* wout  = wzp  + (size_t)NDEPTH*ZPW*EE;
  __bf16* wm1   = wout + (size_t)NDEPTH*EE*EE;
  __bf16* wm2   = wm1  + (size_t)NDEPTH*NH*EE;
  __bf16* whead = wm2  + (size_t)NDEPTH*EE*NH;

  f2b_all<<<(int)(STOT/4/256), 256, 0, stream>>>(z_w, p_w, out_w, mlp_w1, mlp_w2, head_w, wzp);

  sinemb_kernel<<<(NB*EE+255)/256, 256, 0, stream>>>(timesteps, emb);
  time_mlp1<<<NB*NH/4, 256, 0, stream>>>(emb, time_w1, time_b1, thid);
  time_mlp2<<<NB*EE/4, 256, 0, stream>>>(thid, time_w2, time_b2, emb);
  embed_kernel<<<M_ROWS*EE/256, 256, 0, stream>>>(tokens, tok_emb, emb, x);

  const int scan_grid = NB*EE/4;

  for (int i=0;i<NDEPTH;i++){
    const float* dtw = dtp_w + (size_t)i*EE*RR;
    const float* dtb = dtp_b + i*EE;
    const float* cwp = conv_w + (size_t)i*EE*4;
    const float* al  = A_log + (size_t)i*EE*NS;
    ln_kernel<<<M_ROWS/4, 256, 0, stream>>>(x, ln1_g + i*EE, ln1_b + i*EE, xnb);
    gemm_bf16<BE_STORE_ZP,64,64><<<14*32, 256, 0, stream>>>(
        xnb, wzp + (size_t)i*ZPW*EE, nullptr, zgb, dtun, cpf, ZPW, EE, 14, 32);
    scan_fused<<<scan_grid, 256, 0, stream>>>(xnb, dtun, dtw, dtb, cwp, al,
        D_param + i*EE, cpf, zgb, gb);
    gemm_bf16<BE_RESID,64,64><<<12*32, 256, 0, stream>>>(
        gb, wout + (size_t)i*EE*EE, nullptr, x, nullptr, nullptr, EE, EE, 12, 32);
    ln_kernel<<<M_ROWS/4, 256, 0, stream>>>(x, ln2_g + i*EE, ln2_b + i*EE, xnb);
    gemm_bf16<BE_BIAS_GELU_B16,64,128><<<24*32, 256, 0, stream>>>(
        xnb, wm1 + (size_t)i*NH*EE, mlp_b1 + i*NH, hidb, nullptr, nullptr, NH, EE, 24, 32);
    gemm_bf16<BE_BIAS_RESID,64,64><<<12*32, 256, 0, stream>>>(
        hidb, wm2 + (size_t)i*EE*NH, mlp_b2 + i*EE, x, nullptr, nullptr, EE, NH, 12, 32);
  }
  ln_kernel<<<M_ROWS/4, 256, 0, stream>>>(x, lnout_g, lnout_b, xnb);
  gemm_head3p<<<(NV/128)*(M_ROWS/256), 512, 0, stream>>>(xnb, whead, head_b, out);
}